// Round 1
// baseline (3807.320 us; speedup 1.0000x reference)
//
#include <hip/hip_runtime.h>
#include <cstdint>
#include <cstddef>

#define NN 20000
#define EE 320000
#define FF 128
#define RR 32
#define TE 16   // edges per workgroup in msg kernel

__device__ __forceinline__ float swishf(float x) {
    return x / (1.f + __expf(-x));
}

// ---------------------------------------------------------------------------
// Kernel 1: edge geometry + compaction of active edges (r in [0.3, 5.0))
// Stores per active edge: i, j, sh[8] (sh1[3]+sh2[5]), rbf[32] (fc folded in)
// ---------------------------------------------------------------------------
__global__ __launch_bounds__(256) void geom_kernel(
    const float* __restrict__ pos, const int* __restrict__ eidx,
    const float* __restrict__ freq,
    int* __restrict__ ei, int* __restrict__ ej,
    float* __restrict__ sh, float* __restrict__ rbf, int* __restrict__ cnt)
{
    int e = blockIdx.x * 256 + threadIdx.x;
    if (e >= EE) return;
    int i = eidx[e], j = eidx[EE + e];
    float dx = pos[3*j+0] - pos[3*i+0];
    float dy = pos[3*j+1] - pos[3*i+1];
    float dz = pos[3*j+2] - pos[3*i+2];
    float r = sqrtf(dx*dx + dy*dy + dz*dz + 1e-12f);
    if (!(r >= 0.3f && r < 5.0f)) return;          // masked edge: contributes 0
    int slot = atomicAdd(cnt, 1);
    ei[slot] = i; ej[slot] = j;
    float ir = 1.f / (r + 1e-6f);
    float x = dx*ir, y = dy*ir, z = dz*ir;
    const float s3 = 1.7320508075688772f, s5 = 2.23606797749979f, s15 = 3.872983346207417f;
    float* shp = sh + (size_t)slot * 8;
    shp[0] = s3*y; shp[1] = s3*z; shp[2] = s3*x;
    shp[3] = s15*x*y; shp[4] = s15*y*z; shp[5] = 0.5f*s5*(3.f*z*z - 1.f);
    shp[6] = s15*z*x; shp[7] = 0.5f*s15*(x*x - y*y);
    float fc = 0.5f * (cosf(3.14159265358979323846f * r * 0.2f) + 1.f);
    float pref = 0.6324555320336759f * fc * ir;    // sqrt(2/5) * fc / (r+1e-6)
    float* rp = rbf + (size_t)slot * RR;
    for (int k = 0; k < RR; k++) rp[k] = pref * sinf(freq[k] * r * 0.2f);
}

// ---------------------------------------------------------------------------
// Kernel 2: S = swish(emb_table[z] @ emb_W + emb_b)
// ---------------------------------------------------------------------------
__global__ __launch_bounds__(128) void embed_kernel(
    const int* __restrict__ z, const float* __restrict__ emb_table,
    const float* __restrict__ emb_W, const float* __restrict__ emb_b,
    float* __restrict__ S)
{
    int n = blockIdx.x;
    int f = threadIdx.x;
    __shared__ float row[FF];
    row[f] = emb_table[(size_t)z[n]*FF + f];
    __syncthreads();
    float acc = emb_b[f];
    for (int k = 0; k < FF; k++) acc += row[k] * emb_W[k*FF + f];
    S[(size_t)n*FF + f] = swishf(acc);
}

// ---------------------------------------------------------------------------
// Kernel 3 (per block b): fused edge pipeline + atomic scatter
//   h = swish(rbf@Wf1+bf1); w = h@Wf2 ; src = swish(Sj@Wsrc); u = Sj@Wu
//   mS = wS*src -> aggS[i] ; m1o/m1e/m2e = sh x (wk*uk) -> aggT[i]
// 256 threads: f = tid&127, half = tid>>7.
//   half 0 threads own w-cols [0:128) (wS) & [256:384) (w2), outputs src,u2
//   half 1 threads own w-cols [128:256) (w1) & [384:512) (w3), outputs u1,u3
// ---------------------------------------------------------------------------
__global__ __launch_bounds__(256) void msg_kernel(
    const float* __restrict__ S,
    const int* __restrict__ ei, const int* __restrict__ ej,
    const float* __restrict__ sh, const float* __restrict__ rbf,
    const int* __restrict__ cnt,
    const float* __restrict__ Wf1, const float* __restrict__ bf1,
    const float* __restrict__ Wf2, const float* __restrict__ Wsrc,
    const float* __restrict__ Wu,
    float* __restrict__ aggS, float* __restrict__ aggT)
{
    const int Ea = *cnt;
    const int base = blockIdx.x * TE;
    if (base >= Ea) return;
    const int nval = min(TE, Ea - base);
    const int tid = threadIdx.x;
    const int f = tid & (FF-1);
    const int half = tid >> 7;

    __shared__ float rbf_s[TE][RR];
    __shared__ float h_s[TE][FF];
    __shared__ float sj_s[TE][FF];
    __shared__ float sh_s[TE][8];
    __shared__ int   i_s[TE];

    for (int t = tid; t < TE*RR; t += 256) {
        int e = t >> 5;
        rbf_s[e][t & (RR-1)] = (e < nval) ? rbf[(size_t)(base+e)*RR + (t & (RR-1))] : 0.f;
    }
    if (tid < TE*8) {
        int e = tid >> 3;
        sh_s[e][tid & 7] = (e < nval) ? sh[(size_t)(base+e)*8 + (tid & 7)] : 0.f;
    }
    if (tid < TE) i_s[tid] = (tid < nval) ? ei[base + tid] : 0;
    for (int t = tid; t < TE*FF; t += 256) {
        int e = t >> 7, ff = t & (FF-1);
        sj_s[e][ff] = (e < nval) ? S[(size_t)ej[base+e]*FF + ff] : 0.f;
    }
    __syncthreads();

    // phase 1: h = swish(rbf @ Wf1 + bf1); each thread does its f for 8 edges
    {
        float hacc[8];
        const int e0 = half * 8;
        float bb = bf1[f];
        #pragma unroll
        for (int k = 0; k < 8; k++) hacc[k] = bb;
        for (int r = 0; r < RR; r++) {
            float wv = Wf1[r*FF + f];
            #pragma unroll
            for (int k = 0; k < 8; k++) hacc[k] += rbf_s[e0+k][r] * wv;
        }
        #pragma unroll
        for (int k = 0; k < 8; k++) h_s[e0+k][f] = swishf(hacc[k]);
    }
    __syncthreads();

    // phase 2: w = h @ Wf2 ; thread owns cols tid and tid+256, all TE edges
    float wa[TE], wb[TE];
    #pragma unroll
    for (int e = 0; e < TE; e++) { wa[e] = 0.f; wb[e] = 0.f; }
    for (int fp = 0; fp < FF; fp++) {
        float c0 = Wf2[fp*512 + tid];
        float c1 = Wf2[fp*512 + 256 + tid];
        #pragma unroll
        for (int e = 0; e < TE; e++) {
            float hv = h_s[e][fp];          // LDS broadcast
            wa[e] += hv * c0;
            wb[e] += hv * c1;
        }
    }

    // phase 3: half 0: src=Sj@Wsrc[:,f], u2=Sj@Wu[:,F+f]
    //          half 1: u1=Sj@Wu[:,f],   u3=Sj@Wu[:,2F+f]
    float pa[TE], pb[TE];
    #pragma unroll
    for (int e = 0; e < TE; e++) { pa[e] = 0.f; pb[e] = 0.f; }
    const float* WA = (half == 0) ? (Wsrc + f) : (Wu + f);
    const float* WB = (half == 0) ? (Wu + FF + f) : (Wu + 2*FF + f);
    const int strideA = (half == 0) ? FF : 3*FF;
    const int strideB = 3*FF;
    for (int fp = 0; fp < FF; fp++) {
        float ca = WA[(size_t)fp * strideA];
        float cb = WB[(size_t)fp * strideB];
        #pragma unroll
        for (int e = 0; e < TE; e++) {
            float sj = sj_s[e][fp];         // LDS broadcast
            pa[e] += sj * ca;
            pb[e] += sj * cb;
        }
    }

    // phase 4: scatter (static unroll + predication to keep arrays in regs)
    if (half == 0) {
        #pragma unroll
        for (int e = 0; e < TE; e++) if (e < nval) {
            int i = i_s[e];
            float ms = wa[e] * swishf(pa[e]);              // wS * swish(src)
            atomicAdd(&aggS[(size_t)i*FF + f], ms);
            float v = wb[e] * pb[e];                       // w2 * u2 -> rows 3..5
            size_t bT = ((size_t)i*11 + 3)*FF + f;
            atomicAdd(&aggT[bT        ], sh_s[e][0]*v);
            atomicAdd(&aggT[bT +   FF ], sh_s[e][1]*v);
            atomicAdd(&aggT[bT + 2*FF ], sh_s[e][2]*v);
        }
    } else {
        #pragma unroll
        for (int e = 0; e < TE; e++) if (e < nval) {
            int i = i_s[e];
            float v1 = wa[e] * pa[e];                      // w1 * u1 -> rows 0..2
            size_t bT = (size_t)i*11*FF + f;
            atomicAdd(&aggT[bT        ], sh_s[e][0]*v1);
            atomicAdd(&aggT[bT +   FF ], sh_s[e][1]*v1);
            atomicAdd(&aggT[bT + 2*FF ], sh_s[e][2]*v1);
            float v3 = wb[e] * pb[e];                      // w3 * u3 -> rows 6..10
            size_t bT2 = ((size_t)i*11 + 6)*FF + f;
            atomicAdd(&aggT[bT2        ], sh_s[e][3]*v3);
            atomicAdd(&aggT[bT2 +   FF ], sh_s[e][4]*v3);
            atomicAdd(&aggT[bT2 + 2*FF ], sh_s[e][5]*v3);
            atomicAdd(&aggT[bT2 + 3*FF ], sh_s[e][6]*v3);
            atomicAdd(&aggT[bT2 + 4*FF ], sh_s[e][7]*v3);
        }
    }
}

// ---------------------------------------------------------------------------
// Kernel 4 (per block b): node update
//   Tin = T + aggT; T1o/T1e/T2e = Tin@W*; T = concat; inv = sum-of-squares;
//   S += swish([aggS, inv] @ Wup)
// ---------------------------------------------------------------------------
__global__ __launch_bounds__(128) void node_kernel(
    const float* __restrict__ aggS, const float* __restrict__ aggT,
    const float* __restrict__ W1o, const float* __restrict__ W1e,
    const float* __restrict__ W2e, const float* __restrict__ Wup,
    float* __restrict__ S, float* __restrict__ T)
{
    int n = blockIdx.x;
    int f = threadIdx.x;
    __shared__ float tin[11][FF];
    __shared__ float x_s[512];
    size_t bT = (size_t)n*11*FF;
    for (int m = 0; m < 11; m++) tin[m][f] = T[bT + m*FF + f] + aggT[bT + m*FF + f];
    x_s[f] = aggS[(size_t)n*FF + f];
    __syncthreads();

    float tout[11];
    float inv0 = 0.f, inv1 = 0.f, inv2 = 0.f;
    #pragma unroll
    for (int m = 0; m < 3; m++) {
        float a = 0.f;
        for (int fp = 0; fp < FF; fp++) a += tin[m][fp] * W1o[fp*FF + f];
        tout[m] = a; inv0 += a*a;
    }
    #pragma unroll
    for (int m = 0; m < 3; m++) {
        float a = 0.f;
        for (int fp = 0; fp < FF; fp++) a += tin[3+m][fp] * W1e[fp*FF + f];
        tout[3+m] = a; inv1 += a*a;
    }
    #pragma unroll
    for (int m = 0; m < 5; m++) {
        float a = 0.f;
        for (int fp = 0; fp < FF; fp++) a += tin[6+m][fp] * W2e[fp*FF + f];
        tout[6+m] = a; inv2 += a*a;
    }
    #pragma unroll
    for (int m = 0; m < 11; m++) T[bT + m*FF + f] = tout[m];
    x_s[FF + f] = inv0; x_s[2*FF + f] = inv1; x_s[3*FF + f] = inv2;
    __syncthreads();

    float a = 0.f;
    for (int g = 0; g < 512; g++) a += x_s[g] * Wup[g*FF + f];
    S[(size_t)n*FF + f] += swishf(a);
}

// ---------------------------------------------------------------------------
extern "C" void kernel_launch(void* const* d_in, const int* in_sizes, int n_in,
                              void* d_out, int out_size, void* d_ws, size_t ws_size,
                              hipStream_t stream)
{
    const int*   z         = (const int*)  d_in[0];
    const float* pos       = (const float*)d_in[1];
    const int*   eidx      = (const int*)  d_in[2];
    const float* emb_table = (const float*)d_in[3];
    const float* emb_W     = (const float*)d_in[4];
    const float* emb_b     = (const float*)d_in[5];
    const float* freq      = (const float*)d_in[6];
    const float* Wf1       = (const float*)d_in[7];
    const float* bf1       = (const float*)d_in[8];
    const float* Wf2       = (const float*)d_in[9];
    const float* Wsrc      = (const float*)d_in[10];
    const float* Wu        = (const float*)d_in[11];
    const float* W1o       = (const float*)d_in[12];
    const float* W1e       = (const float*)d_in[13];
    const float* W2e       = (const float*)d_in[14];
    const float* Wup       = (const float*)d_in[15];

    float* S = (float*)d_out;                  // (N,F)
    float* T = S + (size_t)NN*FF;              // (N,11,F) -> reshaped (N,11F)

    char* w = (char*)d_ws;
    int*   cnt  = (int*)w;               w += 256;
    int*   ei   = (int*)w;               w += (size_t)EE*4;
    int*   ej   = (int*)w;               w += (size_t)EE*4;
    float* sh   = (float*)w;             w += (size_t)EE*8*4;
    float* rbf  = (float*)w;             w += (size_t)EE*RR*4;
    float* aggS = (float*)w;             w += (size_t)NN*FF*4;
    float* aggT = (float*)w;             w += (size_t)NN*11*FF*4;
    // total ws use ~176 MB

    hipMemsetAsync(cnt, 0, 4, stream);
    hipMemsetAsync(T, 0, (size_t)NN*11*FF*4, stream);

    geom_kernel<<<(EE + 255)/256, 256, 0, stream>>>(pos, eidx, freq, ei, ej, sh, rbf, cnt);
    embed_kernel<<<NN, 128, 0, stream>>>(z, emb_table, emb_W, emb_b, S);

    for (int b = 0; b < 3; b++) {
        // aggS and aggT are contiguous: one combined clear
        hipMemsetAsync(aggS, 0, (size_t)NN*FF*4 + (size_t)NN*11*FF*4, stream);
        msg_kernel<<<(EE + TE - 1)/TE, 256, 0, stream>>>(
            S, ei, ej, sh, rbf, cnt,
            Wf1 + (size_t)b*RR*FF, bf1 + (size_t)b*FF, Wf2 + (size_t)b*FF*512,
            Wsrc + (size_t)b*FF*FF, Wu + (size_t)b*FF*384,
            aggS, aggT);
        node_kernel<<<NN, 128, 0, stream>>>(
            aggS, aggT,
            W1o + (size_t)b*FF*FF, W1e + (size_t)b*FF*FF, W2e + (size_t)b*FF*FF,
            Wup + (size_t)b*512*FF, S, T);
    }
}

// Round 2
// 2288.176 us; speedup vs baseline: 1.6639x; 1.6639x over previous
//
#include <hip/hip_runtime.h>
#include <cstdint>
#include <cstddef>

#define NN 20000
#define EE 320000
#define FF 128
#define RR 32
#define TE 16   // edges per workgroup in msg kernel

typedef float  f32x4  __attribute__((ext_vector_type(4)));
typedef short  bf16x8 __attribute__((ext_vector_type(8)));

__device__ __forceinline__ float swishf(float x) {
    return x / (1.f + __expf(-x));
}
__device__ __forceinline__ unsigned short f2bf(float f) {
    unsigned int u = __builtin_bit_cast(unsigned int, f);
    u = (u + 0x7FFFu + ((u >> 16) & 1u)) >> 16;
    return (unsigned short)u;
}
__device__ __forceinline__ float bf2f(unsigned short h) {
    unsigned int u = ((unsigned int)h) << 16;
    return __builtin_bit_cast(float, u);
}

// ---------------------------------------------------------------------------
// Kernel 1: edge geometry + compaction of active edges (r in [0.3, 5.0))
// Stores per active edge: i, j, sh[8], (r, pref) — rbf recomputed in msg.
// ---------------------------------------------------------------------------
__global__ __launch_bounds__(256) void geom_kernel(
    const float* __restrict__ pos, const int* __restrict__ eidx,
    int* __restrict__ ei, int* __restrict__ ej,
    float* __restrict__ sh, float2* __restrict__ rp, int* __restrict__ cnt)
{
    int e = blockIdx.x * 256 + threadIdx.x;
    if (e >= EE) return;
    int i = eidx[e], j = eidx[EE + e];
    float dx = pos[3*j+0] - pos[3*i+0];
    float dy = pos[3*j+1] - pos[3*i+1];
    float dz = pos[3*j+2] - pos[3*i+2];
    float r = sqrtf(dx*dx + dy*dy + dz*dz + 1e-12f);
    if (!(r >= 0.3f && r < 5.0f)) return;          // masked edge: contributes 0
    int slot = atomicAdd(cnt, 1);
    ei[slot] = i; ej[slot] = j;
    float ir = 1.f / (r + 1e-6f);
    float x = dx*ir, y = dy*ir, z = dz*ir;
    const float s3 = 1.7320508075688772f, s5 = 2.23606797749979f, s15 = 3.872983346207417f;
    float* shp = sh + (size_t)slot * 8;
    shp[0] = s3*y; shp[1] = s3*z; shp[2] = s3*x;
    shp[3] = s15*x*y; shp[4] = s15*y*z; shp[5] = 0.5f*s5*(3.f*z*z - 1.f);
    shp[6] = s15*z*x; shp[7] = 0.5f*s15*(x*x - y*y);
    float fc = 0.5f * (cosf(3.14159265358979323846f * r * 0.2f) + 1.f);
    float pref = 0.6324555320336759f * fc * ir;    // sqrt(2/5) * fc / (r+1e-6)
    rp[slot] = make_float2(r, pref);
}

// ---------------------------------------------------------------------------
// Kernel 2: S = swish(emb_table[z] @ emb_W + emb_b)
// ---------------------------------------------------------------------------
__global__ __launch_bounds__(128) void embed_kernel(
    const int* __restrict__ z, const float* __restrict__ emb_table,
    const float* __restrict__ emb_W, const float* __restrict__ emb_b,
    float* __restrict__ S)
{
    int n = blockIdx.x;
    int f = threadIdx.x;
    __shared__ float row[FF];
    row[f] = emb_table[(size_t)z[n]*FF + f];
    __syncthreads();
    float acc = emb_b[f];
    for (int k = 0; k < FF; k++) acc += row[k] * emb_W[k*FF + f];
    S[(size_t)n*FF + f] = swishf(acc);
}

// ---------------------------------------------------------------------------
// Kernel 2b: pack weights into MFMA B-fragment order, bf16 hi/lo split.
// For matrix W (K x 128): dst[((ct*(K/32)+ks)*64+lane)*8+e] =
//   bf16( W[(ks*32+(lane>>4)*8+e)*128 + ct*16+(lane&15)] )
// Layout per layer (elems): W1o@0, W1e@16384, W2e@32768, Wup@49152; stride 114688.
// ---------------------------------------------------------------------------
__global__ __launch_bounds__(256) void pack_kernel(
    const float* __restrict__ W1o, const float* __restrict__ W1e,
    const float* __restrict__ W2e, const float* __restrict__ Wup,
    unsigned short* __restrict__ ph, unsigned short* __restrict__ pl)
{
    int t = blockIdx.x * 256 + threadIdx.x;
    if (t >= 3 * 14336) return;
    int b = t / 14336, r = t % 14336;
    const float* src; int nks; size_t dstoff;
    if (r < 6144) {
        int mat = r / 2048, rr = r % 2048;
        src = (mat == 0 ? W1o : mat == 1 ? W1e : W2e) + (size_t)b * 16384;
        nks = 4;
        dstoff = (size_t)b * 114688 + (size_t)mat * 16384 + (size_t)rr * 8;
        r = rr;
    } else {
        int rr = r - 6144;
        src = Wup + (size_t)b * 65536;
        nks = 16;
        dstoff = (size_t)b * 114688 + 49152 + (size_t)rr * 8;
        r = rr;
    }
    int lane = r & 63;
    int fi = r >> 6;
    int ks = fi % nks, ct = fi / nks;
    int col = ct * 16 + (lane & 15);
    int kb = ks * 32 + (lane >> 4) * 8;
    #pragma unroll
    for (int e = 0; e < 8; e++) {
        float v = src[(size_t)(kb + e) * 128 + col];
        unsigned short h = f2bf(v);
        ph[dstoff + e] = h;
        pl[dstoff + e] = f2bf(v - bf2f(h));
    }
}

// ---------------------------------------------------------------------------
// Kernel 3 (per block b): fused edge pipeline + atomic scatter (fp32, unchanged
// except rbf is recomputed from (r, pref)).
// ---------------------------------------------------------------------------
__global__ __launch_bounds__(256) void msg_kernel(
    const float* __restrict__ S,
    const int* __restrict__ ei, const int* __restrict__ ej,
    const float* __restrict__ sh, const float2* __restrict__ rp,
    const int* __restrict__ cnt, const float* __restrict__ freq,
    const float* __restrict__ Wf1, const float* __restrict__ bf1,
    const float* __restrict__ Wf2, const float* __restrict__ Wsrc,
    const float* __restrict__ Wu,
    float* __restrict__ aggS, float* __restrict__ aggT)
{
    const int Ea = *cnt;
    const int base = blockIdx.x * TE;
    if (base >= Ea) return;
    const int nval = min(TE, Ea - base);
    const int tid = threadIdx.x;
    const int f = tid & (FF-1);
    const int half = tid >> 7;

    __shared__ float  rbf_s[TE][RR];
    __shared__ float  h_s[TE][FF];
    __shared__ float  sj_s[TE][FF];
    __shared__ float  sh_s[TE][8];
    __shared__ float2 rp_s[TE];
    __shared__ int    i_s[TE];

    if (tid < TE*8) {
        int e = tid >> 3;
        sh_s[e][tid & 7] = (e < nval) ? sh[(size_t)(base+e)*8 + (tid & 7)] : 0.f;
    }
    if (tid < TE) {
        i_s[tid]  = (tid < nval) ? ei[base + tid] : 0;
        rp_s[tid] = (tid < nval) ? rp[base + tid] : make_float2(0.f, 0.f);
    }
    for (int t = tid; t < TE*FF; t += 256) {
        int e = t >> 7, ff = t & (FF-1);
        sj_s[e][ff] = (e < nval) ? S[(size_t)ej[base+e]*FF + ff] : 0.f;
    }
    __syncthreads();
    for (int t = tid; t < TE*RR; t += 256) {
        int e = t >> 5, k = t & (RR-1);
        float2 rr = rp_s[e];
        rbf_s[e][k] = rr.y * sinf(freq[k] * rr.x * 0.2f);
    }
    __syncthreads();

    // phase 1: h = swish(rbf @ Wf1 + bf1)
    {
        float hacc[8];
        const int e0 = half * 8;
        float bb = bf1[f];
        #pragma unroll
        for (int k = 0; k < 8; k++) hacc[k] = bb;
        for (int r = 0; r < RR; r++) {
            float wv = Wf1[r*FF + f];
            #pragma unroll
            for (int k = 0; k < 8; k++) hacc[k] += rbf_s[e0+k][r] * wv;
        }
        #pragma unroll
        for (int k = 0; k < 8; k++) h_s[e0+k][f] = swishf(hacc[k]);
    }
    __syncthreads();

    // phase 2: w = h @ Wf2 ; thread owns cols tid and tid+256
    float wa[TE], wb[TE];
    #pragma unroll
    for (int e = 0; e < TE; e++) { wa[e] = 0.f; wb[e] = 0.f; }
    for (int fp = 0; fp < FF; fp++) {
        float c0 = Wf2[fp*512 + tid];
        float c1 = Wf2[fp*512 + 256 + tid];
        #pragma unroll
        for (int e = 0; e < TE; e++) {
            float hv = h_s[e][fp];
            wa[e] += hv * c0;
            wb[e] += hv * c1;
        }
    }

    // phase 3: half 0: src=Sj@Wsrc[:,f], u2=Sj@Wu[:,F+f]
    //          half 1: u1=Sj@Wu[:,f],   u3=Sj@Wu[:,2F+f]
    float pa[TE], pb[TE];
    #pragma unroll
    for (int e = 0; e < TE; e++) { pa[e] = 0.f; pb[e] = 0.f; }
    const float* WA = (half == 0) ? (Wsrc + f) : (Wu + f);
    const float* WB = (half == 0) ? (Wu + FF + f) : (Wu + 2*FF + f);
    const int strideA = (half == 0) ? FF : 3*FF;
    const int strideB = 3*FF;
    for (int fp = 0; fp < FF; fp++) {
        float ca = WA[(size_t)fp * strideA];
        float cb = WB[(size_t)fp * strideB];
        #pragma unroll
        for (int e = 0; e < TE; e++) {
            float sj = sj_s[e][fp];
            pa[e] += sj * ca;
            pb[e] += sj * cb;
        }
    }

    // phase 4: scatter
    if (half == 0) {
        #pragma unroll
        for (int e = 0; e < TE; e++) if (e < nval) {
            int i = i_s[e];
            float ms = wa[e] * swishf(pa[e]);
            atomicAdd(&aggS[(size_t)i*FF + f], ms);
            float v = wb[e] * pb[e];
            size_t bT = ((size_t)i*11 + 3)*FF + f;
            atomicAdd(&aggT[bT        ], sh_s[e][0]*v);
            atomicAdd(&aggT[bT +   FF ], sh_s[e][1]*v);
            atomicAdd(&aggT[bT + 2*FF ], sh_s[e][2]*v);
        }
    } else {
        #pragma unroll
        for (int e = 0; e < TE; e++) if (e < nval) {
            int i = i_s[e];
            float v1 = wa[e] * pa[e];
            size_t bT = (size_t)i*11*FF + f;
            atomicAdd(&aggT[bT        ], sh_s[e][0]*v1);
            atomicAdd(&aggT[bT +   FF ], sh_s[e][1]*v1);
            atomicAdd(&aggT[bT + 2*FF ], sh_s[e][2]*v1);
            float v3 = wb[e] * pb[e];
            size_t bT2 = ((size_t)i*11 + 6)*FF + f;
            atomicAdd(&aggT[bT2        ], sh_s[e][3]*v3);
            atomicAdd(&aggT[bT2 +   FF ], sh_s[e][4]*v3);
            atomicAdd(&aggT[bT2 + 2*FF ], sh_s[e][5]*v3);
            atomicAdd(&aggT[bT2 + 3*FF ], sh_s[e][6]*v3);
            atomicAdd(&aggT[bT2 + 4*FF ], sh_s[e][7]*v3);
        }
    }
}

// ---------------------------------------------------------------------------
// Kernel 4 (per block b, per m-group g): T-GEMM via MFMA (bf16 hi/lo split).
//   Tin = (addT ? T : 0) + aggT ;  T[:,g-rows,:] = Tin @ Wg ; inv slice = sum T^2
// Block: 16 nodes, 256 threads (4 waves), wave w owns cols [32w, 32w+32).
// A staged fp32 in LDS [GSIZE][16][132] (pad -> 2-way banks only).
// ---------------------------------------------------------------------------
template<int GSIZE>
__global__ __launch_bounds__(256) void tgemm_kernel(
    const float* __restrict__ aggT,
    const unsigned short* __restrict__ Wh, const unsigned short* __restrict__ Wl,
    float* __restrict__ T, float* __restrict__ inv,
    int goff, int invoff, int addT)
{
    __shared__ float stage[GSIZE][16][132];
    const int tid = threadIdx.x;
    const int n0 = blockIdx.x * 16;

    const int total = GSIZE * 16 * 32;   // float4 count
    for (int idx = tid; idx < total; idx += 256) {
        int mg  = idx >> 9;
        int rem = idx & 511;
        int row = rem >> 5;
        int k4  = (rem & 31) << 2;
        size_t g = (((size_t)(n0 + row) * 11 + goff + mg) << 7) + k4;
        float4 v = *(const float4*)&aggT[g];
        if (addT) {
            float4 tv = *(const float4*)&T[g];
            v.x += tv.x; v.y += tv.y; v.z += tv.z; v.w += tv.w;
        }
        *(float4*)&stage[mg][row][k4] = v;
    }
    __syncthreads();

    const int lane = tid & 63;
    const int wid  = tid >> 6;
    const int row  = lane & 15;
    const int k0   = (lane >> 4) * 8;

    f32x4 acc[GSIZE][2];
    #pragma unroll
    for (int mg = 0; mg < GSIZE; mg++) {
        acc[mg][0] = (f32x4){0.f, 0.f, 0.f, 0.f};
        acc[mg][1] = (f32x4){0.f, 0.f, 0.f, 0.f};
    }

    #pragma unroll
    for (int ks = 0; ks < 4; ks++) {
        bf16x8 ah[GSIZE], al[GSIZE];
        #pragma unroll
        for (int mg = 0; mg < GSIZE; mg++) {
            const float* sp = &stage[mg][row][ks*32 + k0];
            float v0[4], v1[4];
            *(float4*)v0 = *(const float4*)sp;
            *(float4*)v1 = *(const float4*)(sp + 4);
            #pragma unroll
            for (int e = 0; e < 4; e++) {
                unsigned short h0 = f2bf(v0[e]);
                ah[mg][e]   = (short)h0;
                al[mg][e]   = (short)f2bf(v0[e] - bf2f(h0));
                unsigned short h1 = f2bf(v1[e]);
                ah[mg][4+e] = (short)h1;
                al[mg][4+e] = (short)f2bf(v1[e] - bf2f(h1));
            }
        }
        #pragma unroll
        for (int cti = 0; cti < 2; cti++) {
            const int ct = wid * 2 + cti;
            size_t boff = (((size_t)ct * 4 + ks) * 64 + lane) * 8;
            bf16x8 bh = *(const bf16x8*)(Wh + boff);
            bf16x8 bl = *(const bf16x8*)(Wl + boff);
            #pragma unroll
            for (int mg = 0; mg < GSIZE; mg++) {
                acc[mg][cti] = __builtin_amdgcn_mfma_f32_16x16x32_bf16(ah[mg], bh, acc[mg][cti], 0, 0, 0);
                acc[mg][cti] = __builtin_amdgcn_mfma_f32_16x16x32_bf16(al[mg], bh, acc[mg][cti], 0, 0, 0);
                acc[mg][cti] = __builtin_amdgcn_mfma_f32_16x16x32_bf16(ah[mg], bl, acc[mg][cti], 0, 0, 0);
            }
        }
    }

    // epilogue: write T rows + inv slice (D mapping: col=lane&15, row=(lane>>4)*4+q)
    #pragma unroll
    for (int cti = 0; cti < 2; cti++) {
        const int ct = wid * 2 + cti;
        const int fc = ct * 16 + (lane & 15);
        #pragma unroll
        for (int q = 0; q < 4; q++) {
            const int n = n0 + (lane >> 4) * 4 + q;
            float iv = 0.f;
            #pragma unroll
            for (int mg = 0; mg < GSIZE; mg++) {
                float o = acc[mg][cti][q];
                T[(((size_t)n * 11 + goff + mg) << 7) + fc] = o;
                iv += o * o;
            }
            inv[(size_t)n * 384 + invoff + fc] = iv;
        }
    }
}

// ---------------------------------------------------------------------------
// Kernel 5 (per block b): S += swish([aggS | inv] @ Wup)  — MFMA hi/lo split.
// Block: 16 nodes, 4 waves, wave w -> cols [32w, 32w+32), K = 512.
// ---------------------------------------------------------------------------
__global__ __launch_bounds__(256) void sgemm2_kernel(
    const float* __restrict__ aggS, const float* __restrict__ inv,
    const unsigned short* __restrict__ Wh, const unsigned short* __restrict__ Wl,
    float* __restrict__ S)
{
    __shared__ float stage[16][516];
    const int tid = threadIdx.x;
    const int n0 = blockIdx.x * 16;

    for (int idx = tid; idx < 16 * 128; idx += 256) {
        int row = idx >> 7;
        int k4  = (idx & 127) << 2;
        float4 v;
        if (k4 < 128) v = *(const float4*)&aggS[((size_t)(n0 + row) << 7) + k4];
        else          v = *(const float4*)&inv[(size_t)(n0 + row) * 384 + (k4 - 128)];
        *(float4*)&stage[row][k4] = v;
    }
    __syncthreads();

    const int lane = tid & 63;
    const int wid  = tid >> 6;
    const int row  = lane & 15;
    const int k0   = (lane >> 4) * 8;

    f32x4 acc[2];
    acc[0] = (f32x4){0.f, 0.f, 0.f, 0.f};
    acc[1] = (f32x4){0.f, 0.f, 0.f, 0.f};

    for (int ks = 0; ks < 16; ks++) {
        const float* sp = &stage[row][ks*32 + k0];
        float v0[4], v1[4];
        *(float4*)v0 = *(const float4*)sp;
        *(float4*)v1 = *(const float4*)(sp + 4);
        bf16x8 ah, al;
        #pragma unroll
        for (int e = 0; e < 4; e++) {
            unsigned short h0 = f2bf(v0[e]);
            ah[e]   = (short)h0;
            al[e]   = (short)f2bf(v0[e] - bf2f(h0));
            unsigned short h1 = f2bf(v1[e]);
            ah[4+e] = (short)h1;
            al[4+e] = (short)f2bf(v1[e] - bf2f(h1));
        }
        #pragma unroll
        for (int cti = 0; cti < 2; cti++) {
            const int ct = wid * 2 + cti;
            size_t boff = (((size_t)ct * 16 + ks) * 64 + lane) * 8;
            bf16x8 bh = *(const bf16x8*)(Wh + boff);
            bf16x8 bl = *(const bf16x8*)(Wl + boff);
            acc[cti] = __builtin_amdgcn_mfma_f32_16x16x32_bf16(ah, bh, acc[cti], 0, 0, 0);
            acc[cti] = __builtin_amdgcn_mfma_f32_16x16x32_bf16(al, bh, acc[cti], 0, 0, 0);
            acc[cti] = __builtin_amdgcn_mfma_f32_16x16x32_bf16(ah, bl, acc[cti], 0, 0, 0);
        }
    }

    #pragma unroll
    for (int cti = 0; cti < 2; cti++) {
        const int ct = wid * 2 + cti;
        const int fc = ct * 16 + (lane & 15);
        #pragma unroll
        for (int q = 0; q < 4; q++) {
            const int n = n0 + (lane >> 4) * 4 + q;
            size_t o = ((size_t)n << 7) + fc;
            S[o] += swishf(acc[cti][q]);
        }
    }
}

// ---------------------------------------------------------------------------
extern "C" void kernel_launch(void* const* d_in, const int* in_sizes, int n_in,
                              void* d_out, int out_size, void* d_ws, size_t ws_size,
                              hipStream_t stream)
{
    const int*   z         = (const int*)  d_in[0];
    const float* pos       = (const float*)d_in[1];
    const int*   eidx      = (const int*)  d_in[2];
    const float* emb_table = (const float*)d_in[3];
    const float* emb_W     = (const float*)d_in[4];
    const float* emb_b     = (const float*)d_in[5];
    const float* freq      = (const float*)d_in[6];
    const float* Wf1       = (const float*)d_in[7];
    const float* bf1       = (const float*)d_in[8];
    const float* Wf2       = (const float*)d_in[9];
    const float* Wsrc      = (const float*)d_in[10];
    const float* Wu        = (const float*)d_in[11];
    const float* W1o       = (const float*)d_in[12];
    const float* W1e       = (const float*)d_in[13];
    const float* W2e       = (const float*)d_in[14];
    const float* Wup       = (const float*)d_in[15];

    float* S = (float*)d_out;                  // (N,F)
    float* T = S + (size_t)NN*FF;              // (N,11,F)

    char* w = (char*)d_ws;
    int*    cnt  = (int*)w;            w += 256;
    int*    ei   = (int*)w;            w += (size_t)EE*4;
    int*    ej   = (int*)w;            w += (size_t)EE*4;
    float*  sh   = (float*)w;          w += (size_t)EE*8*4;
    float2* rp   = (float2*)w;         w += (size_t)EE*2*4;
    float*  aggS = (float*)w;          w += (size_t)NN*FF*4;
    float*  aggT = (float*)w;          w += (size_t)NN*11*FF*4;
    float*  inv  = (float*)w;          w += (size_t)NN*384*4;
    unsigned short* packH = (unsigned short*)w;  w += (size_t)344064*2;
    unsigned short* packL = (unsigned short*)w;  w += (size_t)344064*2;
    // total ws use ~171 MB

    hipMemsetAsync(cnt, 0, 4, stream);

    geom_kernel<<<(EE + 255)/256, 256, 0, stream>>>(pos, eidx, ei, ej, sh, rp, cnt);
    embed_kernel<<<NN, 128, 0, stream>>>(z, emb_table, emb_W, emb_b, S);
    pack_kernel<<<(3*14336 + 255)/256, 256, 0, stream>>>(W1o, W1e, W2e, Wup, packH, packL);

    for (int b = 0; b < 3; b++) {
        hipMemsetAsync(aggS, 0, (size_t)NN*FF*4 + (size_t)NN*11*FF*4, stream);
        msg_kernel<<<(EE + TE - 1)/TE, 256, 0, stream>>>(
            S, ei, ej, sh, rp, cnt, freq,
            Wf1 + (size_t)b*RR*FF, bf1 + (size_t)b*FF, Wf2 + (size_t)b*FF*512,
            Wsrc + (size_t)b*FF*FF, Wu + (size_t)b*FF*384,
            aggS, aggT);

        const unsigned short* H = packH + (size_t)b*114688;
        const unsigned short* L = packL + (size_t)b*114688;
        tgemm_kernel<3><<<NN/16, 256, 0, stream>>>(aggT, H +     0, L +     0, T, inv, 0,   0, b > 0);
        tgemm_kernel<3><<<NN/16, 256, 0, stream>>>(aggT, H + 16384, L + 16384, T, inv, 3, 128, b > 0);
        tgemm_kernel<5><<<NN/16, 256, 0, stream>>>(aggT, H + 32768, L + 32768, T, inv, 6, 256, b > 0);
        sgemm2_kernel<<<NN/16, 256, 0, stream>>>(aggS, inv, H + 49152, L + 49152, S);
    }
}

// Round 3
// 985.194 us; speedup vs baseline: 3.8645x; 2.3226x over previous
//
#include <hip/hip_runtime.h>
#include <cstdint>
#include <cstddef>

#define NN 20000
#define EE 320000
#define FF 128
#define RR 32
#define MTE 16   // edges per workgroup in msg kernel

typedef float  f32x4  __attribute__((ext_vector_type(4)));
typedef short  bf16x8 __attribute__((ext_vector_type(8)));

__device__ __forceinline__ float swishf(float x) {
    return x / (1.f + __expf(-x));
}
__device__ __forceinline__ unsigned short f2bf(float f) {
    unsigned int u = __builtin_bit_cast(unsigned int, f);
    u = (u + 0x7FFFu + ((u >> 16) & 1u)) >> 16;
    return (unsigned short)u;
}
__device__ __forceinline__ float bf2f(unsigned short h) {
    unsigned int u = ((unsigned int)h) << 16;
    return __builtin_bit_cast(float, u);
}

// ---------------------------------------------------------------------------
// Pass 1: active-edge degree histogram over destination i
// ---------------------------------------------------------------------------
__global__ __launch_bounds__(256) void geom_deg_kernel(
    const float* __restrict__ pos, const int* __restrict__ eidx,
    int* __restrict__ deg)
{
    int e = blockIdx.x * 256 + threadIdx.x;
    if (e >= EE) return;
    int i = eidx[e], j = eidx[EE + e];
    float dx = pos[3*j+0] - pos[3*i+0];
    float dy = pos[3*j+1] - pos[3*i+1];
    float dz = pos[3*j+2] - pos[3*i+2];
    float r = sqrtf(dx*dx + dy*dy + dz*dz + 1e-12f);
    if (r >= 0.3f && r < 5.0f) atomicAdd(&deg[i], 1);
}

// ---------------------------------------------------------------------------
// Block-wide exclusive scan of deg -> cursor (bin start offsets); cnt[0]=total
// ---------------------------------------------------------------------------
__global__ __launch_bounds__(256) void scan_kernel(
    const int* __restrict__ deg, int* __restrict__ cursor, int* __restrict__ cnt)
{
    __shared__ int part[256];
    const int t = threadIdx.x;
    const int lo = t * 79;
    const int hi = min(lo + 79, NN);
    int s = 0;
    for (int k = lo; k < hi; k++) s += deg[k];
    part[t] = s;
    __syncthreads();
    for (int off = 1; off < 256; off <<= 1) {
        int v = (t >= off) ? part[t - off] : 0;
        __syncthreads();
        part[t] += v;
        __syncthreads();
    }
    int run = (t == 0) ? 0 : part[t - 1];
    for (int k = lo; k < hi; k++) { cursor[k] = run; run += deg[k]; }
    if (t == 255) cnt[0] = part[255];
}

// ---------------------------------------------------------------------------
// Pass 2: recompute geometry, scatter active edges into i-sorted slots.
// Per edge: i, j, sh[8] f32, rbf[32] bf16 (fc/r prefactor folded in)
// ---------------------------------------------------------------------------
__global__ __launch_bounds__(256) void geom_scatter_kernel(
    const float* __restrict__ pos, const int* __restrict__ eidx,
    const float* __restrict__ freq, int* __restrict__ cursor,
    int* __restrict__ ei, int* __restrict__ ej,
    float* __restrict__ sh, unsigned short* __restrict__ rbfq)
{
    int e = blockIdx.x * 256 + threadIdx.x;
    if (e >= EE) return;
    int i = eidx[e], j = eidx[EE + e];
    float dx = pos[3*j+0] - pos[3*i+0];
    float dy = pos[3*j+1] - pos[3*i+1];
    float dz = pos[3*j+2] - pos[3*i+2];
    float r = sqrtf(dx*dx + dy*dy + dz*dz + 1e-12f);
    if (!(r >= 0.3f && r < 5.0f)) return;
    int slot = atomicAdd(&cursor[i], 1);
    ei[slot] = i; ej[slot] = j;
    float ir = 1.f / (r + 1e-6f);
    float x = dx*ir, y = dy*ir, z = dz*ir;
    const float s3 = 1.7320508075688772f, s5 = 2.23606797749979f, s15 = 3.872983346207417f;
    float* shp = sh + (size_t)slot * 8;
    shp[0] = s3*y; shp[1] = s3*z; shp[2] = s3*x;
    shp[3] = s15*x*y; shp[4] = s15*y*z; shp[5] = 0.5f*s5*(3.f*z*z - 1.f);
    shp[6] = s15*z*x; shp[7] = 0.5f*s15*(x*x - y*y);
    float fc = 0.5f * (cosf(3.14159265358979323846f * r * 0.2f) + 1.f);
    float pref = 0.6324555320336759f * fc * ir;
    unsigned short* rp = rbfq + (size_t)slot * RR;
    for (int k = 0; k < RR; k++) rp[k] = f2bf(pref * sinf(freq[k] * r * 0.2f));
}

// ---------------------------------------------------------------------------
// S = swish(emb_table[z] @ emb_W + emb_b)
// ---------------------------------------------------------------------------
__global__ __launch_bounds__(128) void embed_kernel(
    const int* __restrict__ z, const float* __restrict__ emb_table,
    const float* __restrict__ emb_W, const float* __restrict__ emb_b,
    float* __restrict__ S)
{
    int n = blockIdx.x;
    int f = threadIdx.x;
    __shared__ float row[FF];
    row[f] = emb_table[(size_t)z[n]*FF + f];
    __syncthreads();
    float acc = emb_b[f];
    for (int k = 0; k < FF; k++) acc += row[k] * emb_W[k*FF + f];
    S[(size_t)n*FF + f] = swishf(acc);
}

// ---------------------------------------------------------------------------
// Node-weight pack (hi/lo split) — unchanged from round 2 (validated).
// ---------------------------------------------------------------------------
__global__ __launch_bounds__(256) void pack_kernel(
    const float* __restrict__ W1o, const float* __restrict__ W1e,
    const float* __restrict__ W2e, const float* __restrict__ Wup,
    unsigned short* __restrict__ ph, unsigned short* __restrict__ pl)
{
    int t = blockIdx.x * 256 + threadIdx.x;
    if (t >= 3 * 14336) return;
    int b = t / 14336, r = t % 14336;
    const float* src; int nks; size_t dstoff;
    if (r < 6144) {
        int mat = r / 2048, rr = r % 2048;
        src = (mat == 0 ? W1o : mat == 1 ? W1e : W2e) + (size_t)b * 16384;
        nks = 4;
        dstoff = (size_t)b * 114688 + (size_t)mat * 16384 + (size_t)rr * 8;
        r = rr;
    } else {
        int rr = r - 6144;
        src = Wup + (size_t)b * 65536;
        nks = 16;
        dstoff = (size_t)b * 114688 + 49152 + (size_t)rr * 8;
        r = rr;
    }
    int lane = r & 63;
    int fi = r >> 6;
    int ks = fi % nks, ct = fi / nks;
    int col = ct * 16 + (lane & 15);
    int kb = ks * 32 + (lane >> 4) * 8;
    #pragma unroll
    for (int e = 0; e < 8; e++) {
        float v = src[(size_t)(kb + e) * 128 + col];
        unsigned short h = f2bf(v);
        ph[dstoff + e] = h;
        pl[dstoff + e] = f2bf(v - bf2f(h));
    }
}

// ---------------------------------------------------------------------------
// Pack [Wsrc | Wu] (K=128, N=512) into bf16 B-frags, per layer 65536 elems.
// ---------------------------------------------------------------------------
__global__ __launch_bounds__(256) void pack_pu_kernel(
    const float* __restrict__ Wsrc, const float* __restrict__ Wu,
    unsigned short* __restrict__ packPU)
{
    int t = blockIdx.x * 256 + threadIdx.x;
    if (t >= 3 * 8192) return;
    int b = t / 8192, r = t % 8192;
    int lane = r & 63, fi = r >> 6;       // fi = ct*4+ks
    int ks = fi & 3, ct = fi >> 2;
    int kb = ks * 32 + (lane >> 4) * 8;
    int colq = lane & 15;
    const float* src; int col, stride;
    if (ct < 8) { src = Wsrc + (size_t)b * 16384; col = ct*16 + colq; stride = 128; }
    else        { src = Wu   + (size_t)b * 49152; col = (ct-8)*16 + colq; stride = 384; }
    size_t dst = (size_t)b * 65536 + (size_t)fi * 512 + (size_t)lane * 8;
    #pragma unroll
    for (int e = 0; e < 8; e++)
        packPU[dst + e] = f2bf(src[(size_t)(kb + e) * stride + col]);
}

// ---------------------------------------------------------------------------
// Pack Wf2 (K=128, N=512) into bf16 B-frags.
// ---------------------------------------------------------------------------
__global__ __launch_bounds__(256) void pack_f2_kernel(
    const float* __restrict__ Wf2, unsigned short* __restrict__ packF2)
{
    int t = blockIdx.x * 256 + threadIdx.x;
    if (t >= 3 * 8192) return;
    int b = t / 8192, r = t % 8192;
    int lane = r & 63, fi = r >> 6;
    int ks = fi & 3, ct = fi >> 2;
    int kb = ks * 32 + (lane >> 4) * 8;
    int col = ct * 16 + (lane & 15);
    const float* src = Wf2 + (size_t)b * 65536;
    size_t dst = (size_t)b * 65536 + (size_t)fi * 512 + (size_t)lane * 8;
    #pragma unroll
    for (int e = 0; e < 8; e++)
        packF2[dst + e] = f2bf(src[(size_t)(kb + e) * 512 + col]);
}

// ---------------------------------------------------------------------------
// Per-node projection: PU = [swish(S@Wsrc) | S@Wu]  (N x 512, bf16), MFMA.
// 16 nodes/block, 4 waves; wave w owns cols [128w, 128w+128) (ct = 8w..8w+7).
// ---------------------------------------------------------------------------
__global__ __launch_bounds__(256) void proj_kernel(
    const float* __restrict__ S, const unsigned short* __restrict__ packPU,
    unsigned short* __restrict__ PU)
{
    __shared__ float stage[16][132];
    const int tid = threadIdx.x;
    const int n0 = blockIdx.x * 16;

    for (int idx = tid; idx < 512; idx += 256) {
        int row = idx >> 5, k4 = (idx & 31) << 2;
        *(float4*)&stage[row][k4] = *(const float4*)&S[((size_t)(n0 + row) << 7) + k4];
    }
    __syncthreads();

    const int lane = tid & 63;
    const int wid  = tid >> 6;
    const int row  = lane & 15;
    const int k0   = (lane >> 4) * 8;

    f32x4 acc[8];
    #pragma unroll
    for (int c = 0; c < 8; c++) acc[c] = (f32x4){0.f, 0.f, 0.f, 0.f};

    #pragma unroll
    for (int ks = 0; ks < 4; ks++) {
        const float* sp = &stage[row][ks*32 + k0];
        bf16x8 a;
        #pragma unroll
        for (int e = 0; e < 8; e++) a[e] = (short)f2bf(sp[e]);
        #pragma unroll
        for (int cti = 0; cti < 8; cti++) {
            int ct = wid * 8 + cti;
            bf16x8 b = *(const bf16x8*)(packPU + (((size_t)ct * 4 + ks) * 64 + lane) * 8);
            acc[cti] = __builtin_amdgcn_mfma_f32_16x16x32_bf16(a, b, acc[cti], 0, 0, 0);
        }
    }

    #pragma unroll
    for (int cti = 0; cti < 8; cti++) {
        int ct = wid * 8 + cti;
        int col = ct * 16 + (lane & 15);
        #pragma unroll
        for (int q = 0; q < 4; q++) {
            int n = n0 + (lane >> 4) * 4 + q;
            float v = acc[cti][q];
            if (ct < 8) v = swishf(v);       // swish only on the Wsrc block
            PU[(size_t)n * 512 + col] = f2bf(v);
        }
    }
}

// ---------------------------------------------------------------------------
// Message kernel: 16 sorted edges per block.
//  h = swish(rbf@Wf1+bf1) (VALU, K=32) -> LDS bf16
//  w = h@Wf2 (MFMA bf16)  -> LDS w-tile
//  formation: gather PU[j], products, SEGMENTED atomic flush per i-run.
// ---------------------------------------------------------------------------
__global__ __launch_bounds__(256) void msg_kernel(
    const int* __restrict__ cnt,
    const int* __restrict__ ei, const int* __restrict__ ej,
    const float* __restrict__ sh, const unsigned short* __restrict__ rbfq,
    const float* __restrict__ Wf1, const float* __restrict__ bf1,
    const unsigned short* __restrict__ packF2, const unsigned short* __restrict__ PU,
    float* __restrict__ aggS, float* __restrict__ aggT)
{
    const int Ea = cnt[0];
    const int base = blockIdx.x * MTE;
    if (base >= Ea) return;
    const int nval = min(MTE, Ea - base);
    const int tid = threadIdx.x;

    __shared__ float          rbf_s[MTE][RR];
    __shared__ unsigned short h_s[MTE][FF];
    __shared__ unsigned short w_s[MTE][512];
    __shared__ float          sh_s[MTE][8];
    __shared__ int            i_s[MTE];
    __shared__ int            j_s[MTE];

    if (tid < MTE) {
        i_s[tid] = (tid < nval) ? ei[base + tid] : -1;
        j_s[tid] = (tid < nval) ? ej[base + tid] : 0;
    }
    if (tid >= 64 && tid < 64 + MTE*8) {
        int t = tid - 64, e = t >> 3;
        sh_s[e][t & 7] = (e < nval) ? sh[(size_t)(base + e)*8 + (t & 7)] : 0.f;
    }
    for (int t = tid; t < MTE*RR; t += 256) {
        int e = t >> 5, k = t & 31;
        rbf_s[e][k] = (e < nval) ? bf2f(rbfq[(size_t)(base + e)*RR + k]) : 0.f;
    }
    __syncthreads();

    // h = swish(rbf @ Wf1 + bf1): thread f = tid&127 does 8 edges
    {
        const int f = tid & 127, eh = tid >> 7;
        float hacc[8];
        float bb = bf1[f];
        #pragma unroll
        for (int k = 0; k < 8; k++) hacc[k] = bb;
        for (int r = 0; r < RR; r++) {
            float wv = Wf1[r*FF + f];
            #pragma unroll
            for (int k = 0; k < 8; k++) hacc[k] += rbf_s[eh*8 + k][r] * wv;
        }
        #pragma unroll
        for (int k = 0; k < 8; k++) h_s[eh*8 + k][f] = f2bf(swishf(hacc[k]));
    }
    __syncthreads();

    // w = h @ Wf2 via MFMA; wave wid owns cols [128*wid, 128*wid+128)
    {
        const int lane = tid & 63;
        const int wid  = tid >> 6;
        const int ra   = lane & 15;
        const int k0   = (lane >> 4) * 8;
        f32x4 acc[8];
        #pragma unroll
        for (int c = 0; c < 8; c++) acc[c] = (f32x4){0.f, 0.f, 0.f, 0.f};
        #pragma unroll
        for (int ks = 0; ks < 4; ks++) {
            bf16x8 a = *(const bf16x8*)&h_s[ra][ks*32 + k0];
            #pragma unroll
            for (int cti = 0; cti < 8; cti++) {
                int ct = wid * 8 + cti;
                bf16x8 b = *(const bf16x8*)(packF2 + (((size_t)ct * 4 + ks) * 64 + lane) * 8);
                acc[cti] = __builtin_amdgcn_mfma_f32_16x16x32_bf16(a, b, acc[cti], 0, 0, 0);
            }
        }
        #pragma unroll
        for (int cti = 0; cti < 8; cti++) {
            int ct = wid * 8 + cti;
            int col = ct * 16 + (lane & 15);
            #pragma unroll
            for (int q = 0; q < 4; q++)
                w_s[(lane >> 4)*4 + q][col] = f2bf(acc[cti][q]);
        }
    }
    __syncthreads();

    // formation + segmented atomic scatter
    const int f = tid & 127;
    if (tid < 128) {
        // aggS (wS*P) and rows 3..5 (sh1 x (w2*u2))
        float aS = 0.f, a3 = 0.f, a4 = 0.f, a5 = 0.f;
        int cur = i_s[0];
        for (int e = 0; e < nval; e++) {
            int ie = i_s[e];
            if (ie != cur) {
                atomicAdd(&aggS[((size_t)cur << 7) + f], aS);
                size_t bT = (((size_t)cur*11 + 3) << 7) + f;
                atomicAdd(&aggT[bT], a3); atomicAdd(&aggT[bT + 128], a4); atomicAdd(&aggT[bT + 256], a5);
                aS = a3 = a4 = a5 = 0.f; cur = ie;
            }
            const unsigned short* pu = PU + (size_t)j_s[e] * 512;
            float wS = bf2f(w_s[e][f]),       P  = bf2f(pu[f]);
            float w2 = bf2f(w_s[e][256 + f]), U2 = bf2f(pu[256 + f]);
            aS += wS * P;
            float v = w2 * U2;
            a3 += sh_s[e][0]*v; a4 += sh_s[e][1]*v; a5 += sh_s[e][2]*v;
        }
        atomicAdd(&aggS[((size_t)cur << 7) + f], aS);
        size_t bT = (((size_t)cur*11 + 3) << 7) + f;
        atomicAdd(&aggT[bT], a3); atomicAdd(&aggT[bT + 128], a4); atomicAdd(&aggT[bT + 256], a5);
    } else {
        // rows 0..2 (sh1 x (w1*u1)) and rows 6..10 (sh2 x (w3*u3))
        float a0 = 0.f, a1 = 0.f, a2 = 0.f;
        float a6 = 0.f, a7 = 0.f, a8 = 0.f, a9 = 0.f, a10 = 0.f;
        int cur = i_s[0];
        for (int e = 0; e < nval; e++) {
            int ie = i_s[e];
            if (ie != cur) {
                size_t bT = (((size_t)cur*11) << 7) + f;
                atomicAdd(&aggT[bT], a0); atomicAdd(&aggT[bT + 128], a1); atomicAdd(&aggT[bT + 256], a2);
                size_t bT2 = (((size_t)cur*11 + 6) << 7) + f;
                atomicAdd(&aggT[bT2], a6); atomicAdd(&aggT[bT2 + 128], a7); atomicAdd(&aggT[bT2 + 256], a8);
                atomicAdd(&aggT[bT2 + 384], a9); atomicAdd(&aggT[bT2 + 512], a10);
                a0 = a1 = a2 = a6 = a7 = a8 = a9 = a10 = 0.f; cur = ie;
            }
            const unsigned short* pu = PU + (size_t)j_s[e] * 512;
            float w1 = bf2f(w_s[e][128 + f]), U1 = bf2f(pu[128 + f]);
            float w3 = bf2f(w_s[e][384 + f]), U3 = bf2f(pu[384 + f]);
            float v1 = w1 * U1;
            a0 += sh_s[e][0]*v1; a1 += sh_s[e][1]*v1; a2 += sh_s[e][2]*v1;
            float v3 = w3 * U3;
            a6 += sh_s[e][3]*v3; a7 += sh_s[e][4]*v3; a8 += sh_s[e][5]*v3;
            a9 += sh_s[e][6]*v3; a10 += sh_s[e][7]*v3;
        }
        size_t bT = (((size_t)cur*11) << 7) + f;
        atomicAdd(&aggT[bT], a0); atomicAdd(&aggT[bT + 128], a1); atomicAdd(&aggT[bT + 256], a2);
        size_t bT2 = (((size_t)cur*11 + 6) << 7) + f;
        atomicAdd(&aggT[bT2], a6); atomicAdd(&aggT[bT2 + 128], a7); atomicAdd(&aggT[bT2 + 256], a8);
        atomicAdd(&aggT[bT2 + 384], a9); atomicAdd(&aggT[bT2 + 512], a10);
    }
}

// ---------------------------------------------------------------------------
// T-GEMM via MFMA (bf16 hi/lo split) — unchanged from round 2 (validated).
// ---------------------------------------------------------------------------
template<int GSIZE>
__global__ __launch_bounds__(256) void tgemm_kernel(
    const float* __restrict__ aggT,
    const unsigned short* __restrict__ Wh, const unsigned short* __restrict__ Wl,
    float* __restrict__ T, float* __restrict__ inv,
    int goff, int invoff, int addT)
{
    __shared__ float stage[GSIZE][16][132];
    const int tid = threadIdx.x;
    const int n0 = blockIdx.x * 16;

    const int total = GSIZE * 16 * 32;
    for (int idx = tid; idx < total; idx += 256) {
        int mg  = idx >> 9;
        int rem = idx & 511;
        int row = rem >> 5;
        int k4  = (rem & 31) << 2;
        size_t g = (((size_t)(n0 + row) * 11 + goff + mg) << 7) + k4;
        float4 v = *(const float4*)&aggT[g];
        if (addT) {
            float4 tv = *(const float4*)&T[g];
            v.x += tv.x; v.y += tv.y; v.z += tv.z; v.w += tv.w;
        }
        *(float4*)&stage[mg][row][k4] = v;
    }
    __syncthreads();

    const int lane = tid & 63;
    const int wid  = tid >> 6;
    const int row  = lane & 15;
    const int k0   = (lane >> 4) * 8;

    f32x4 acc[GSIZE][2];
    #pragma unroll
    for (int mg = 0; mg < GSIZE; mg++) {
        acc[mg][0] = (f32x4){0.f, 0.f, 0.f, 0.f};
        acc[mg][1] = (f32x4){0.f, 0.f, 0.f, 0.f};
    }

    #pragma unroll
    for (int ks = 0; ks < 4; ks++) {
        bf16x8 ah[GSIZE], al[GSIZE];
        #pragma unroll
        for (int mg = 0; mg < GSIZE; mg++) {
            const float* sp = &stage[mg][row][ks*32 + k0];
            float v0[4], v1[4];
            *(float4*)v0 = *(const float4*)sp;
            *(float4*)v1 = *(const float4*)(sp + 4);
            #pragma unroll
            for (int e = 0; e < 4; e++) {
                unsigned short h0 = f2bf(v0[e]);
                ah[mg][e]   = (short)h0;
                al[mg][e]   = (short)f2bf(v0[e] - bf2f(h0));
                unsigned short h1 = f2bf(v1[e]);
                ah[mg][4+e] = (short)h1;
                al[mg][4+e] = (short)f2bf(v1[e] - bf2f(h1));
            }
        }
        #pragma unroll
        for (int cti = 0; cti < 2; cti++) {
            const int ct = wid * 2 + cti;
            size_t boff = (((size_t)ct * 4 + ks) * 64 + lane) * 8;
            bf16x8 bh = *(const bf16x8*)(Wh + boff);
            bf16x8 bl = *(const bf16x8*)(Wl + boff);
            #pragma unroll
            for (int mg = 0; mg < GSIZE; mg++) {
                acc[mg][cti] = __builtin_amdgcn_mfma_f32_16x16x32_bf16(ah[mg], bh, acc[mg][cti], 0, 0, 0);
                acc[mg][cti] = __builtin_amdgcn_mfma_f32_16x16x32_bf16(al[mg], bh, acc[mg][cti], 0, 0, 0);
                acc[mg][cti] = __builtin_amdgcn_mfma_f32_16x16x32_bf16(ah[mg], bl, acc[mg][cti], 0, 0, 0);
            }
        }
    }

    #pragma unroll
    for (int cti = 0; cti < 2; cti++) {
        const int ct = wid * 2 + cti;
        const int fc = ct * 16 + (lane & 15);
        #pragma unroll
        for (int q = 0; q < 4; q++) {
            const int n = n0 + (lane >> 4) * 4 + q;
            float iv = 0.f;
            #pragma unroll
            for (int mg = 0; mg < GSIZE; mg++) {
                float o = acc[mg][cti][q];
                T[(((size_t)n * 11 + goff + mg) << 7) + fc] = o;
                iv += o * o;
            }
            inv[(size_t)n * 384 + invoff + fc] = iv;
        }
    }
}

// ---------------------------------------------------------------------------
// S += swish([aggS | inv] @ Wup) — unchanged from round 2 (validated).
// ---------------------------------------------------------------------------
__global__ __launch_bounds__(256) void sgemm2_kernel(
    const float* __restrict__ aggS, const float* __restrict__ inv,
    const unsigned short* __restrict__ Wh, const unsigned short* __restrict__ Wl,
    float* __restrict__ S)
{
    __shared__ float stage[16][516];
    const int tid = threadIdx.x;
    const int n0 = blockIdx.x * 16;

    for (int idx = tid; idx < 16 * 128; idx += 256) {
        int row = idx >> 7;
        int k4  = (idx & 127) << 2;
        float4 v;
        if (k4 < 128) v = *(const float4*)&aggS[((size_t)(n0 + row) << 7) + k4];
        else          v = *(const float4*)&inv[(size_t)(n0 + row) * 384 + (k4 - 128)];
        *(float4*)&stage[row][k4] = v;
    }
    __syncthreads();

    const int lane = tid & 63;
    const int wid  = tid >> 6;
    const int row  = lane & 15;
    const int k0   = (lane >> 4) * 8;

    f32x4 acc[2];
    acc[0] = (f32x4){0.f, 0.f, 0.f, 0.f};
    acc[1] = (f32x4){0.f, 0.f, 0.f, 0.f};

    for (int ks = 0; ks < 16; ks++) {
        const float* sp = &stage[row][ks*32 + k0];
        float v0[4], v1[4];
        *(float4*)v0 = *(const float4*)sp;
        *(float4*)v1 = *(const float4*)(sp + 4);
        bf16x8 ah, al;
        #pragma unroll
        for (int e = 0; e < 4; e++) {
            unsigned short h0 = f2bf(v0[e]);
            ah[e]   = (short)h0;
            al[e]   = (short)f2bf(v0[e] - bf2f(h0));
            unsigned short h1 = f2bf(v1[e]);
            ah[4+e] = (short)h1;
            al[4+e] = (short)f2bf(v1[e] - bf2f(h1));
        }
        #pragma unroll
        for (int cti = 0; cti < 2; cti++) {
            const int ct = wid * 2 + cti;
            size_t boff = (((size_t)ct * 16 + ks) * 64 + lane) * 8;
            bf16x8 bh = *(const bf16x8*)(Wh + boff);
            bf16x8 bl = *(const bf16x8*)(Wl + boff);
            acc[cti] = __builtin_amdgcn_mfma_f32_16x16x32_bf16(ah, bh, acc[cti], 0, 0, 0);
            acc[cti] = __builtin_amdgcn_mfma_f32_16x16x32_bf16(al, bh, acc[cti], 0, 0, 0);
            acc[cti] = __builtin_amdgcn_mfma_f32_16x16x32_bf16(ah, bl, acc[cti], 0, 0, 0);
        }
    }

    #pragma unroll
    for (int cti = 0; cti < 2; cti++) {
        const int ct = wid * 2 + cti;
        const int fc = ct * 16 + (lane & 15);
        #pragma unroll
        for (int q = 0; q < 4; q++) {
            const int n = n0 + (lane >> 4) * 4 + q;
            size_t o = ((size_t)n << 7) + fc;
            S[o] += swishf(acc[cti][q]);
        }
    }
}

// ---------------------------------------------------------------------------
extern "C" void kernel_launch(void* const* d_in, const int* in_sizes, int n_in,
                              void* d_out, int out_size, void* d_ws, size_t ws_size,
                              hipStream_t stream)
{
    const int*   z         = (const int*)  d_in[0];
    const float* pos       = (const float*)d_in[1];
    const int*   eidx      = (const int*)  d_in[2];
    const float* emb_table = (const float*)d_in[3];
    const float* emb_W     = (const float*)d_in[4];
    const float* emb_b     = (const float*)d_in[5];
    const float* freq      = (const float*)d_in[6];
    const float* Wf1       = (const float*)d_in[7];
    const float* bf1       = (const float*)d_in[8];
    const float* Wf2       = (const float*)d_in[9];
    const float* Wsrc      = (const float*)d_in[10];
    const float* Wu        = (const float*)d_in[11];
    const float* W1o       = (const float*)d_in[12];
    const float* W1e       = (const float*)d_in[13];
    const float* W2e       = (const float*)d_in[14];
    const float* Wup       = (const float*)d_in[15];

    float* S = (float*)d_out;                  // (N,F)
    float* T = S + (size_t)NN*FF;              // (N,11,F)

    char* w = (char*)d_ws;
    int*   cnt    = (int*)w;                      w += 256;
    int*   deg    = (int*)w;                      w += (size_t)NN*4 + 128;
    int*   cursor = (int*)w;                      w += (size_t)NN*4 + 128;
    int*   ei     = (int*)w;                      w += (size_t)EE*4;
    int*   ej     = (int*)w;                      w += (size_t)EE*4;
    float* sh     = (float*)w;                    w += (size_t)EE*8*4;
    unsigned short* rbfq = (unsigned short*)w;    w += (size_t)EE*RR*2;
    unsigned short* PU   = (unsigned short*)w;    w += (size_t)NN*512*2;
    float* aggS   = (float*)w;                    w += (size_t)NN*FF*4;
    float* aggT   = (float*)w;                    w += (size_t)NN*11*FF*4;
    float* inv    = (float*)w;                    w += (size_t)NN*384*4;
    unsigned short* packH  = (unsigned short*)w;  w += (size_t)344064*2;
    unsigned short* packL  = (unsigned short*)w;  w += (size_t)344064*2;
    unsigned short* packPU = (unsigned short*)w;  w += (size_t)3*65536*2;
    unsigned short* packF2 = (unsigned short*)w;  w += (size_t)3*65536*2;
    // total ws use ~210 MB

    hipMemsetAsync(deg, 0, (size_t)NN*4, stream);

    geom_deg_kernel<<<(EE + 255)/256, 256, 0, stream>>>(pos, eidx, deg);
    scan_kernel<<<1, 256, 0, stream>>>(deg, cursor, cnt);
    geom_scatter_kernel<<<(EE + 255)/256, 256, 0, stream>>>(pos, eidx, freq, cursor, ei, ej, sh, rbfq);
    embed_kernel<<<NN, 128, 0, stream>>>(z, emb_table, emb_W, emb_b, S);
    pack_kernel<<<(3*14336 + 255)/256, 256, 0, stream>>>(W1o, W1e, W2e, Wup, packH, packL);
    pack_pu_kernel<<<(3*8192 + 255)/256, 256, 0, stream>>>(Wsrc, Wu, packPU);
    pack_f2_kernel<<<(3*8192 + 255)/256, 256, 0, stream>>>(Wf2, packF2);

    for (int b = 0; b < 3; b++) {
        hipMemsetAsync(aggS, 0, (size_t)NN*FF*4 + (size_t)NN*11*FF*4, stream);
        proj_kernel<<<NN/16, 256, 0, stream>>>(S, packPU + (size_t)b*65536, PU);
        msg_kernel<<<(EE + MTE - 1)/MTE, 256, 0, stream>>>(
            cnt, ei, ej, sh, rbfq,
            Wf1 + (size_t)b*RR*FF, bf1 + (size_t)b*FF,
            packF2 + (size_t)b*65536, PU, aggS, aggT);

        const unsigned short* H = packH + (size_t)b*114688;
        const unsigned short* L = packL + (size_t)b*114688;
        tgemm_kernel<3><<<NN/16, 256, 0, stream>>>(aggT, H +     0, L +     0, T, inv, 0,   0, b > 0);
        tgemm_kernel<3><<<NN/16, 256, 0, stream>>>(aggT, H + 16384, L + 16384, T, inv, 3, 128, b > 0);
        tgemm_kernel<5><<<NN/16, 256, 0, stream>>>(aggT, H + 32768, L + 32768, T, inv, 6, 256, b > 0);
        sgemm2_kernel<<<NN/16, 256, 0, stream>>>(aggS, inv, H + 49152, L + 49152, S);
    }
}